// Round 1
// baseline (35.995 us; speedup 1.0000x reference)
//
#include <hip/hip_runtime.h>

#define B_DIM 8
#define T_DIM 16
#define H_IN 500
#define W_IN 500
#define HP 512
#define WP 512
#define NPH 127
#define NPW 127
#define STEP 4
#define SP 8
#define LDS_STRIDE 516   // 512 + 4: breaks the 8-way bank conflict of the transposed gather

// ---------------------------------------------------------------------------
// K1: output[b,h,w] = sum_t x[b,t,h,w] * weight[t, h&3, w&3], over padded 512x512.
// One thread per (b, h, w0) with w0 = 4-column float4 group. Writes full field to
// ws (zeros in the pad region) and the 500x500 crop to d_out.
// ---------------------------------------------------------------------------
__global__ __launch_bounds__(256) void k_conv(const float* __restrict__ in,
                                              const float* __restrict__ wgt,
                                              float* __restrict__ ws,
                                              float* __restrict__ crop) {
    __shared__ float4 wlds[T_DIM * 4];  // weight[t][r][0..3] as float4
    int tid = threadIdx.x;
    if (tid < T_DIM * 4) wlds[tid] = reinterpret_cast<const float4*>(wgt)[tid];
    __syncthreads();

    int idx = blockIdx.x * 256 + tid;          // 8*512*128 total
    int w4  = idx & 127;                        // float4 column group
    int h   = (idx >> 7) & 511;
    int b   = idx >> 16;
    int w0  = w4 * 4;

    float4 acc = {0.f, 0.f, 0.f, 0.f};
    bool valid = (h < H_IN) && (w0 < W_IN);     // 500 % 4 == 0, so group-exact
    if (valid) {
        const float* base = in + (size_t)b * T_DIM * (H_IN * W_IN) + h * W_IN + w0;
        int hr = h & 3;
        #pragma unroll
        for (int t = 0; t < T_DIM; ++t) {
            float4 xv = *reinterpret_cast<const float4*>(base + (size_t)t * (H_IN * W_IN));
            float4 wv = wlds[t * 4 + hr];
            acc.x += xv.x * wv.x;
            acc.y += xv.y * wv.y;
            acc.z += xv.z * wv.z;
            acc.w += xv.w * wv.w;
        }
    }
    reinterpret_cast<float4*>(ws)[idx] = acc;   // ws layout [b][512][512]
    if (valid) {
        *reinterpret_cast<float4*>(crop + ((size_t)b * H_IN + h) * W_IN + w0) = acc;
    }
}

// ---------------------------------------------------------------------------
// K2: one block per (b, ph). Stage rows 4ph..4ph+7 into LDS (padded stride),
// then write patches[b, ph*127+pw, j*8+i] = field[4ph+i, 4pw+j] coalesced.
// ---------------------------------------------------------------------------
__global__ __launch_bounds__(256) void k_patch(const float* __restrict__ ws,
                                               float* __restrict__ patches) {
    __shared__ float lds[SP * LDS_STRIDE];
    int blk = blockIdx.x;
    int ph  = blk % NPH;
    int b   = blk / NPH;
    int tid = threadIdx.x;

    const float* src = ws + ((size_t)b * HP + ph * STEP) * WP;
    #pragma unroll
    for (int k = 0; k < 4; ++k) {
        int e = tid + k * 256;                  // 1024 float4 = 8 rows x 128
        int r = e >> 7;
        int c = (e & 127) * 4;
        float4 v = *reinterpret_cast<const float4*>(src + r * WP + c);
        *reinterpret_cast<float4*>(&lds[r * LDS_STRIDE + c]) = v;
    }
    __syncthreads();

    float* dst = patches + ((size_t)b * NPH * NPW + (size_t)ph * NPW) * 64;
    for (int e4 = tid; e4 < NPW * 16; e4 += 256) {   // 2032 float4 per block
        int i0 = (e4 & 1) * 4;
        int j  = (e4 >> 1) & 7;
        int pw = e4 >> 4;
        float4 v;
        v.x = lds[(i0 + 0) * LDS_STRIDE + pw * 4 + j];
        v.y = lds[(i0 + 1) * LDS_STRIDE + pw * 4 + j];
        v.z = lds[(i0 + 2) * LDS_STRIDE + pw * 4 + j];
        v.w = lds[(i0 + 3) * LDS_STRIDE + pw * 4 + j];
        reinterpret_cast<float4*>(dst)[e4] = v;
    }
}

// ---------------------------------------------------------------------------
// Fallback (if ws too small): fused per-(b,ph) kernel, recomputes its 8 rows.
// Overlapping rows are computed twice (identical values) -> benign dup writes.
// ---------------------------------------------------------------------------
__global__ __launch_bounds__(256) void k_fused(const float* __restrict__ in,
                                               const float* __restrict__ wgt,
                                               float* __restrict__ patches,
                                               float* __restrict__ crop) {
    __shared__ float lds[SP * LDS_STRIDE];
    __shared__ float4 wlds[T_DIM * 4];
    int tid = threadIdx.x;
    if (tid < T_DIM * 4) wlds[tid] = reinterpret_cast<const float4*>(wgt)[tid];
    __syncthreads();

    int blk = blockIdx.x;
    int ph  = blk % NPH;
    int b   = blk / NPH;

    #pragma unroll
    for (int k = 0; k < 4; ++k) {
        int e = tid + k * 256;
        int r = e >> 7;
        int c = (e & 127) * 4;
        int h = ph * STEP + r;
        float4 acc = {0.f, 0.f, 0.f, 0.f};
        if (h < H_IN && c < W_IN) {
            const float* base = in + (size_t)b * T_DIM * (H_IN * W_IN) + h * W_IN + c;
            int hr = h & 3;
            #pragma unroll
            for (int t = 0; t < T_DIM; ++t) {
                float4 xv = *reinterpret_cast<const float4*>(base + (size_t)t * (H_IN * W_IN));
                float4 wv = wlds[t * 4 + hr];
                acc.x += xv.x * wv.x;
                acc.y += xv.y * wv.y;
                acc.z += xv.z * wv.z;
                acc.w += xv.w * wv.w;
            }
            *reinterpret_cast<float4*>(crop + ((size_t)b * H_IN + h) * W_IN + c) = acc;
        }
        *reinterpret_cast<float4*>(&lds[r * LDS_STRIDE + c]) = acc;
    }
    __syncthreads();

    float* dst = patches + ((size_t)b * NPH * NPW + (size_t)ph * NPW) * 64;
    for (int e4 = tid; e4 < NPW * 16; e4 += 256) {
        int i0 = (e4 & 1) * 4;
        int j  = (e4 >> 1) & 7;
        int pw = e4 >> 4;
        float4 v;
        v.x = lds[(i0 + 0) * LDS_STRIDE + pw * 4 + j];
        v.y = lds[(i0 + 1) * LDS_STRIDE + pw * 4 + j];
        v.z = lds[(i0 + 2) * LDS_STRIDE + pw * 4 + j];
        v.w = lds[(i0 + 3) * LDS_STRIDE + pw * 4 + j];
        reinterpret_cast<float4*>(dst)[e4] = v;
    }
}

extern "C" void kernel_launch(void* const* d_in, const int* in_sizes, int n_in,
                              void* d_out, int out_size, void* d_ws, size_t ws_size,
                              hipStream_t stream) {
    const float* in  = (const float*)d_in[0];
    const float* wgt = (const float*)d_in[1];
    float* out     = (float*)d_out;
    float* patches = out;                                      // 8*16129*64 floats
    float* crop    = out + (size_t)B_DIM * NPH * NPW * 64;     // then 8*500*500

    size_t ws_need = (size_t)B_DIM * HP * WP * sizeof(float);  // 8.4 MB
    if (ws_size >= ws_need) {
        float* ws = (float*)d_ws;
        k_conv <<<(B_DIM * HP * (WP / 4)) / 256, 256, 0, stream>>>(in, wgt, ws, crop);
        k_patch<<<B_DIM * NPH, 256, 0, stream>>>(ws, patches);
    } else {
        k_fused<<<B_DIM * NPH, 256, 0, stream>>>(in, wgt, patches, crop);
    }
}

// Round 2
// 30.493 us; speedup vs baseline: 1.1804x; 1.1804x over previous
//
#include <hip/hip_runtime.h>

#define B_DIM 8
#define T_DIM 16
#define H_IN 500
#define W_IN 500
#define NPH 127
#define NPW 127
#define STEP 4
#define LSTR 516   // 512+4 LDS row stride: keeps transposed gathers <=2-way (free)

// One block per (b, q): owns output rows [8q, 8q+8). Computes them once
// (each input element read exactly once), writes the crop, and emits:
//   - full patch ph=2q            (rows 8q..8q+7  == band rows 0..7)
//   - half patch ph=2q+1, i=0..3  (rows 8q+4..8q+7 == band rows 4..7)
//   - half patch ph=2q-1, i=4..7  (rows 8q..8q+3   == band rows 0..3)
// Patch layout patches[b, ph*127+pw, j*8+i]: each (pw,j,half) is one float4.
__global__ __launch_bounds__(256) void k_band(const float* __restrict__ in,
                                              const float* __restrict__ wgt,
                                              float* __restrict__ patches,
                                              float* __restrict__ crop) {
    __shared__ float lds[8 * LSTR];
    __shared__ float4 wlds[T_DIM * 4];     // weight[t][r][0..3]
    int tid = threadIdx.x;
    if (tid < T_DIM * 4) wlds[tid] = reinterpret_cast<const float4*>(wgt)[tid];

    // XCD-chunked swizzle: 512 blocks = 8 XCD * 64; adjacent bands (which
    // co-own the interleaved odd-patch cachelines) land on the same XCD L2.
    int orig = blockIdx.x;
    int n = (orig & 7) * 64 + (orig >> 3);
    int q = n & 63;
    int b = n >> 6;
    __syncthreads();

    // ---- Phase A: compute 8 rows x 512 cols into LDS (+ crop write) ----
    #pragma unroll
    for (int k = 0; k < 4; ++k) {
        int e = tid + k * 256;                 // 0..1023 float4 slots
        int r = e >> 7;                        // band row 0..7
        int c = (e & 127) * 4;                 // col 0..508
        int h = q * 8 + r;
        float4 acc = {0.f, 0.f, 0.f, 0.f};
        if (h < H_IN && c < W_IN) {            // 500 % 4 == 0: group-exact
            const float* base = in + (size_t)b * T_DIM * (H_IN * W_IN) + h * W_IN + c;
            int hr = h & 3;
            #pragma unroll
            for (int t = 0; t < T_DIM; ++t) {
                float4 xv = *reinterpret_cast<const float4*>(base + (size_t)t * (H_IN * W_IN));
                float4 wv = wlds[t * 4 + hr];
                acc.x += xv.x * wv.x;
                acc.y += xv.y * wv.y;
                acc.z += xv.z * wv.z;
                acc.w += xv.w * wv.w;
            }
            *reinterpret_cast<float4*>(crop + ((size_t)b * H_IN + h) * W_IN + c) = acc;
        }
        *reinterpret_cast<float4*>(&lds[r * LSTR + c]) = acc;
    }
    __syncthreads();

    // ---- Phase B1: full patch ph=2q (contiguous float4 stores) ----
    {
        float* dst = patches + (((size_t)b * NPH + 2 * q) * NPW) * 64;
        for (int e4 = tid; e4 < NPW * 16; e4 += 256) {
            int i0 = (e4 & 1) * 4;
            int j  = (e4 >> 1) & 7;
            int pw = e4 >> 4;
            int col = pw * STEP + j;
            float4 v;
            v.x = lds[(i0 + 0) * LSTR + col];
            v.y = lds[(i0 + 1) * LSTR + col];
            v.z = lds[(i0 + 2) * LSTR + col];
            v.w = lds[(i0 + 3) * LSTR + col];
            reinterpret_cast<float4*>(dst)[e4] = v;
        }
    }
    // ---- Phase B2: patch ph=2q+1, i=0..3 (from band rows 4..7) ----
    if (q < 63) {
        float* dst = patches + (((size_t)b * NPH + 2 * q + 1) * NPW) * 64;
        for (int e = tid; e < NPW * 8; e += 256) {
            int j  = e & 7;
            int pw = e >> 3;
            int col = pw * STEP + j;
            float4 v;
            v.x = lds[4 * LSTR + col];
            v.y = lds[5 * LSTR + col];
            v.z = lds[6 * LSTR + col];
            v.w = lds[7 * LSTR + col];
            reinterpret_cast<float4*>(dst)[pw * 16 + j * 2] = v;
        }
    }
    // ---- Phase B3: patch ph=2q-1, i=4..7 (from band rows 0..3) ----
    if (q > 0) {
        float* dst = patches + (((size_t)b * NPH + 2 * q - 1) * NPW) * 64;
        for (int e = tid; e < NPW * 8; e += 256) {
            int j  = e & 7;
            int pw = e >> 3;
            int col = pw * STEP + j;
            float4 v;
            v.x = lds[0 * LSTR + col];
            v.y = lds[1 * LSTR + col];
            v.z = lds[2 * LSTR + col];
            v.w = lds[3 * LSTR + col];
            reinterpret_cast<float4*>(dst)[pw * 16 + j * 2 + 1] = v;
        }
    }
}

extern "C" void kernel_launch(void* const* d_in, const int* in_sizes, int n_in,
                              void* d_out, int out_size, void* d_ws, size_t ws_size,
                              hipStream_t stream) {
    const float* in  = (const float*)d_in[0];
    const float* wgt = (const float*)d_in[1];
    float* out     = (float*)d_out;
    float* patches = out;                                      // 8*16129*64 floats
    float* crop    = out + (size_t)B_DIM * NPH * NPW * 64;     // then 8*500*500

    k_band<<<B_DIM * 64, 256, 0, stream>>>(in, wgt, patches, crop);
}